// Round 18
// baseline (190.431 us; speedup 1.0000x reference)
//
#include <hip/hip_runtime.h>
#include <hip/hip_bf16.h>

// Problem geometry
#define N_ROWS 32000   // Q_OUT*Q_IN*NUM_P
#define SB     12      // SCALAR_BASIS
#define FC     720     // FILTER_C
#define FD     2704    // FILTER_DIM
#define OCOLS  2704    // DIM_OUT*DIM_IN
#define OPAD   2816    // padded o (22*128)
#define ANGD   25
#define PDIM   300     // SB * ANGD
#define KST    320     // PDIM padded to 5*64 (main GEMM K)
#define NT     5       // main GEMM K tiles of 64
#define KP     2720    // FD padded to 85*32 (V-GEMM K)
#define NTV    85      // V-GEMM K tiles of 32
#define GPR    (KP/8)  // 340 groups per TPb row

typedef __attribute__((ext_vector_type(8))) short bf16x8;
typedef __attribute__((ext_vector_type(4))) float f32x4;

__device__ __forceinline__ void gload16(const void* g, void* l) {
    __builtin_amdgcn_global_load_lds(
        (const __attribute__((address_space(1))) void*)g,
        (__attribute__((address_space(3))) void*)l, 16, 0, 0);
}

__device__ __forceinline__ void decode_f(int f, int& c, int& j, int& a) {
    if (f < 144)       { c = f;                         j = 0;            a = 0;  }
    else if (f < 960)  { int t = f - 144;  c = 144 + t/3; j = t - (t/3)*3; a = 1;  }
    else if (f < 2000) { int t = f - 960;  c = 416 + t/5; j = t - (t/5)*5; a = 4;  }
    else if (f < 2560) { int t = f - 2000; c = 624 + t/7; j = t - (t/7)*7; a = 9;  }
    else               { int t = f - 2560; c = 704 + t/9; j = t - (t/9)*9; a = 16; }
}

// ---------------------------------------------------------------------------
// Kernel 1 (R14 proven): TP (2704x2704 f32) -> TPb bf16 padded (OPAD x KP).
// ---------------------------------------------------------------------------
__global__ void cvt_M(const float* __restrict__ M, __hip_bfloat16* __restrict__ out)
{
    const int g = blockIdx.x * 256 + threadIdx.x;
    if (g >= OPAD * GPR) return;
    const int o = g / GPR;
    const int k = (g - o * GPR) * 8;
    alignas(16) __hip_bfloat16 tmp[8];
    if (o < OCOLS && k + 8 <= FD) {
        const float4* p = (const float4*)(M + (size_t)o * FD + k);
        float4 x0 = p[0], x1 = p[1];
        tmp[0] = __float2bfloat16(x0.x); tmp[1] = __float2bfloat16(x0.y);
        tmp[2] = __float2bfloat16(x0.z); tmp[3] = __float2bfloat16(x0.w);
        tmp[4] = __float2bfloat16(x1.x); tmp[5] = __float2bfloat16(x1.y);
        tmp[6] = __float2bfloat16(x1.z); tmp[7] = __float2bfloat16(x1.w);
    } else {
        #pragma unroll
        for (int u = 0; u < 8; ++u) {
            float v = (o < OCOLS && k + u < FD) ? M[(size_t)o * FD + k + u] : 0.f;
            tmp[u] = __float2bfloat16(v);
        }
    }
    *(bf16x8*)(out + (size_t)o * KP + k) = *(const bf16x8*)tmp;
}

// ---------------------------------------------------------------------------
// Kernel 2 (R14 proven): Gt[p][f] = match ? W[s(p),c(f)]/sqrt12 : 0.
// ---------------------------------------------------------------------------
__global__ void build_G(const float* __restrict__ W, __hip_bfloat16* __restrict__ Gt)
{
    const int g = blockIdx.x * 256 + threadIdx.x;
    if (g >= KST * GPR) return;
    const int p  = g / GPR;
    const int f0 = (g - p * GPR) * 8;
    const int s     = p / ANGD;
    const int alpha = p - s * ANGD;
    const float inv = 0.28867513459481288f;
    alignas(16) __hip_bfloat16 tmp[8];
    #pragma unroll
    for (int u = 0; u < 8; ++u) {
        const int f = f0 + u;
        float v = 0.f;
        if (p < PDIM && f < FD) {
            int c, j, a;
            decode_f(f, c, j, a);
            if (alpha == a + j) v = W[s * FC + c] * inv;
        }
        tmp[u] = __float2bfloat16(v);
    }
    *(bf16x8*)(Gt + (size_t)p * KP + f0) = *(const bf16x8*)tmp;
}

// ---------------------------------------------------------------------------
// Kernel 3 (R14 proven): X[n, s*25+a] = sk[n,s] * ang[n,a], bf16.
// ---------------------------------------------------------------------------
__global__ void build_X(const float* __restrict__ sk,
                        const float* __restrict__ ang,
                        __hip_bfloat16* __restrict__ X)
{
    const int idx = blockIdx.x * 256 + threadIdx.x;
    if (idx >= N_ROWS * (KST / 8)) return;
    const int n  = idx / (KST / 8);
    const int p0 = (idx - n * (KST / 8)) * 8;
    const float* skn  = sk  + (size_t)n * SB;
    const float* angn = ang + (size_t)n * ANGD;
    alignas(16) __hip_bfloat16 tmp[8];
    #pragma unroll
    for (int u = 0; u < 8; ++u) {
        const int p = p0 + u;
        float v = 0.f;
        if (p < PDIM) {
            const int s = p / ANGD;
            const int a = p - s * ANGD;
            v = skn[s] * angn[a];
        }
        tmp[u] = __float2bfloat16(v);
    }
    *(bf16x8*)(X + (size_t)n * KST + p0) = *(const bf16x8*)tmp;
}

// ---------------------------------------------------------------------------
// Kernel 4 (R14 proven): V-GEMM. V[o,p] = sum_f TPb[o,f] * Gt[p,f].
// ---------------------------------------------------------------------------
__global__ __launch_bounds__(256, 4) void gemm_V(
    const __hip_bfloat16* __restrict__ A,   // TPb: (OPAD, KP)
    const __hip_bfloat16* __restrict__ B,   // Gt:  (KST, KP)
    __hip_bfloat16* __restrict__ V)         // (OPAD, KST)
{
    __shared__ __align__(1024) char lds[24576];
    char* const bufA = lds;
    char* const bufB = lds + 16384;

    const int tid  = threadIdx.x;
    const int wave = tid >> 6;
    const int lane = tid & 63;

    const int bn = blockIdx.x;         // 5 col tiles (64 p each)
    const int bm = blockIdx.y;         // 22 row tiles (128 o each)
    const size_t arow0 = (size_t)bm * 128;
    const size_t brow0 = (size_t)bn * 64;

    const int wr = wave >> 1;
    const int wc = wave & 1;

    const int lrow2 = lane >> 2;
    const int sslot = (((lane & 3) ^ (lrow2 & 3) ^ ((lane >> 4) & 3))) << 4;

    auto STAGE = [&](int t, int half) {
        char* const la = bufA + half * 8192;
        char* const lb = bufB + half * 4096;
        const char* ga = (const char*)A
            + (arow0 + (size_t)(wave * 16 + lrow2)) * (KP * 2)
            + (size_t)t * 64 + sslot;
        gload16(ga,                         la + wave * 1024);
        gload16(ga + (size_t)64 * (KP * 2), la + 4096 + wave * 1024);
        const char* gb = (const char*)B
            + (brow0 + (size_t)(wave * 16 + lrow2)) * (KP * 2)
            + (size_t)t * 64 + sslot;
        gload16(gb, lb + wave * 1024);
    };

    const int rl   = lane & 15;
    const int koct = lane >> 4;
    const int rslot = ((koct ^ (rl & 3) ^ ((rl >> 2) & 3))) << 4;

    STAGE(0, 0);
    STAGE(1, 1);
    asm volatile("s_waitcnt vmcnt(3)" ::: "memory");
    __builtin_amdgcn_s_barrier();

    f32x4 acc[4][2] = {};

    for (int t = 0; t < NTV; ++t) {
        char* const aC = bufA + (t & 1) * 8192;
        char* const bC = bufB + (t & 1) * 4096;

        bf16x8 af[4], bfr[2];
        #pragma unroll
        for (int m = 0; m < 4; ++m) {
            const int r = wr * 64 + m * 16 + rl;
            af[m] = *(const bf16x8*)(aC + r * 64 + rslot);
        }
        #pragma unroll
        for (int n = 0; n < 2; ++n) {
            const int r = wc * 32 + n * 16 + rl;
            bfr[n] = *(const bf16x8*)(bC + r * 64 + rslot);
        }
        asm volatile("s_waitcnt lgkmcnt(0)" ::: "memory");
        __builtin_amdgcn_sched_barrier(0);
        __builtin_amdgcn_s_barrier();

        if (t + 2 < NTV) STAGE(t + 2, t & 1);

        __builtin_amdgcn_s_setprio(1);
        #pragma unroll
        for (int m = 0; m < 4; ++m)
            #pragma unroll
            for (int n = 0; n < 2; ++n)
                acc[m][n] = __builtin_amdgcn_mfma_f32_16x16x32_bf16(
                    bfr[n], af[m], acc[m][n], 0, 0, 0);
        __builtin_amdgcn_s_setprio(0);
        __builtin_amdgcn_sched_barrier(0);

        if (t < NTV - 2)       asm volatile("s_waitcnt vmcnt(3)" ::: "memory");
        else if (t == NTV - 2) asm volatile("s_waitcnt vmcnt(0)" ::: "memory");
        if (t < NTV - 1) __builtin_amdgcn_s_barrier();
    }

    const int obase = (int)arow0 + wr * 64 + rl;
    const int pbase = (int)brow0 + wc * 32 + koct * 4;
    #pragma unroll
    for (int m = 0; m < 4; ++m) {
        const int orow = obase + m * 16;
        #pragma unroll
        for (int n = 0; n < 2; ++n) {
            const int p = pbase + n * 16;
            alignas(8) __hip_bfloat16 t4[4];
            t4[0] = __float2bfloat16(acc[m][n][0]);
            t4[1] = __float2bfloat16(acc[m][n][1]);
            t4[2] = __float2bfloat16(acc[m][n][2]);
            t4[3] = __float2bfloat16(acc[m][n][3]);
            *(uint2*)(V + (size_t)orow * KST + p) = *(const uint2*)t4;
        }
    }
}

// ---------------------------------------------------------------------------
// Kernel 5: main GEMM = R14 structure with B moved LDS -> registers.
// 128x128 tile, 512 threads, 8 waves (2M x 4N, per-wave 64x32, acc[4][2]
// — identical wave decomposition to R14). A staged via swizzled gload_lds
// dbuf (identical). B (V, L2-hot: 250 row-blocks share each panel) read
// direct global->VGPR, named even/odd reg dbuf, full NT=5 unroll (static
// indexing). LDS traffic/block 900 -> ~530 KB. VGPR ~110 < 128 cap of
// __launch_bounds__(512,2) -> 2 blocks/CU preserved.
// vmcnt ledger (STAGE_A=2 loads, LOADB=8): prologue A0(2),B0(8),A1(2) ->
// vmcnt(2) leaves A1. Iter t: LOADB(t+1) +8 ... STAGE_A(t+2) +2; end
// vmcnt(2) retires A(t+1)+B(t+1) (in-order), leaves A(t+2). t==NT-2 ->
// vmcnt(0) (only B(NT-1) outstanding). Epilogue: R14's two-pass LDS-routed
// full-line nt stores (s_c aliases bufA).
// ---------------------------------------------------------------------------
__global__ __launch_bounds__(512, 2) void gemm_bt(
    const __hip_bfloat16* __restrict__ A,   // X: (N_ROWS, KST)
    const __hip_bfloat16* __restrict__ B,   // V: (OPAD, KST)
    float* __restrict__ C)
{
    __shared__ __align__(1024) char lds[34816];
    char* const bufA = lds;            // 2 x 16384 B (A dbuf)
    float* const s_c = (float*)lds;    // epilogue alias: [64][132] f32 (33792 B)

    const int tid  = threadIdx.x;
    const int wave = tid >> 6;         // 0..7
    const int lane = tid & 63;

    const int bn = blockIdx.x;         // 22 col tiles (128 o)
    const int bm = blockIdx.y;         // 250 row tiles (128 n)
    const size_t arow0 = (size_t)bm * 128;
    const size_t brow0 = (size_t)bn * 128;

    const int wr = wave >> 2;          // 0..1 (M half: 64 rows)
    const int wc = wave & 3;           // 0..3 (o quarter: 32 cols)

    // A staging (LDS linear dest; global source pre-swizzled) — R14 exact
    const int lrow  = lane >> 3;
    const int lslot = ((lane & 7) ^ (lrow & 7)) << 4;
    auto STAGE_A = [&](int t, char* lbase) {
        const char* g0 = (const char*)A
            + (arow0 + (size_t)(wave * 8 + lrow)) * (KST * 2)
            + (size_t)t * 128 + lslot;
        gload16(g0,                          lbase + wave * 1024);
        gload16(g0 + (size_t)64 * (KST * 2), lbase + 8192 + wave * 1024);
    };

    // reader constants (swizzle: slot = (ks*4+koct) ^ (row&7); row&7==lane&7)
    const int rl   = lane & 15;
    const int koct = lane >> 4;
    const int sK0 = ((0 * 4 + koct) ^ (lane & 7)) << 4;
    const int sK1 = ((1 * 4 + koct) ^ (lane & 7)) << 4;

    // B direct-global fragment loads (MFMA B-operand layout: row=brow0+
    // wc*32+n*16+rl, k-elems koct*8.. within tile t)
    const char* const Bb = (const char*)B;
    auto LOADB = [&](int t, bf16x8 (&dst)[2][2]) {
        #pragma unroll
        for (int n = 0; n < 2; ++n) {
            const char* bp = Bb
                + (brow0 + (size_t)(wc * 32 + n * 16 + rl)) * (KST * 2)
                + (size_t)t * 128 + koct * 16;
            dst[n][0] = *(const bf16x8*)(bp);
            dst[n][1] = *(const bf16x8*)(bp + 64);
        }
    };

    // prologue: A0 -> buf0, B0 -> regs, A1 -> buf1
    bf16x8 bEven[2][2], bOdd[2][2];
    STAGE_A(0, bufA + 0);
    LOADB(0, bEven);
    STAGE_A(1, bufA + 16384);
    asm volatile("s_waitcnt vmcnt(2)" ::: "memory");
    __builtin_amdgcn_s_barrier();

    f32x4 acc[4][2] = {};   // [m][n]; D^T frags: row=o, col=M

    #pragma unroll
    for (int t = 0; t < NT; ++t) {
        char* const aC = bufA + (t & 1) * 16384;
        bf16x8 (&bcur)[2][2] = (t & 1) ? bOdd : bEven;
        bf16x8 (&bnxt)[2][2] = (t & 1) ? bEven : bOdd;

        if (t + 1 < NT) LOADB(t + 1, bnxt);   // prefetch next B tile to regs

        bf16x8 af[4][2];
        #pragma unroll
        for (int m = 0; m < 4; ++m) {
            const int r = wr * 64 + m * 16 + rl;
            af[m][0] = *(const bf16x8*)(aC + r * 128 + sK0);
            af[m][1] = *(const bf16x8*)(aC + r * 128 + sK1);
        }
        asm volatile("s_waitcnt lgkmcnt(0)" ::: "memory");
        __builtin_amdgcn_sched_barrier(0);
        __builtin_amdgcn_s_barrier();   // all waves done reading this buf

        if (t + 2 < NT) STAGE_A(t + 2, aC);   // refill the buffer just read

        __builtin_amdgcn_s_setprio(1);
        #pragma unroll
        for (int ks = 0; ks < 2; ++ks)
            #pragma unroll
            for (int m = 0; m < 4; ++m)
                #pragma unroll
                for (int n = 0; n < 2; ++n)
                    acc[m][n] = __builtin_amdgcn_mfma_f32_16x16x32_bf16(
                        bcur[n][ks], af[m][ks], acc[m][n], 0, 0, 0);
        __builtin_amdgcn_s_setprio(0);
        __builtin_amdgcn_sched_barrier(0);

        if (t < NT - 2)       asm volatile("s_waitcnt vmcnt(2)" ::: "memory");
        else if (t == NT - 2) asm volatile("s_waitcnt vmcnt(0)" ::: "memory");
        if (t < NT - 1) __builtin_amdgcn_s_barrier();
    }

    // ---- epilogue through LDS (R14 exact): two 64-row passes, nt stores ----
    // acc[m][n]: M = arow0 + wr*64 + m*16 + rl; o = brow0 + wc*32 + n*16 + koct*4
    #pragma unroll
    for (int h = 0; h < 2; ++h) {
        __syncthreads();
        if (wr == h) {
            #pragma unroll
            for (int m = 0; m < 4; ++m) {
                const int row_l = m * 16 + rl;
                #pragma unroll
                for (int n = 0; n < 2; ++n) {
                    const int col = wc * 32 + n * 16 + koct * 4;
                    *(f32x4*)&s_c[row_l * 132 + col] = acc[m][n];
                }
            }
        }
        __syncthreads();
        #pragma unroll
        for (int rr = 0; rr < 4; ++rr) {
            const int idx  = rr * 512 + tid;
            const int row  = idx >> 5;
            const int g4   = (idx & 31) * 4;
            if ((int)brow0 + g4 < OCOLS) {
                const f32x4 v = *(const f32x4*)&s_c[row * 132 + g4];
                __builtin_nontemporal_store(v,
                    (f32x4*)(C + (size_t)(arow0 + h * 64 + row) * OCOLS + brow0 + g4));
            }
        }
    }
}

// ---------------------------------------------------------------------------
extern "C" void kernel_launch(void* const* d_in, const int* in_sizes, int n_in,
                              void* d_out, int out_size, void* d_ws, size_t ws_size,
                              hipStream_t stream)
{
    const float* sk  = (const float*)d_in[0];   // (16,16,125,12)
    const float* ang = (const float*)d_in[1];   // (32000,25)
    const float* W   = (const float*)d_in[2];   // (12,720)
    const float* TP  = (const float*)d_in[3];   // (2704,2704)
    float* out = (float*)d_out;                 // (32000,2704)

    __hip_bfloat16* X   = (__hip_bfloat16*)d_ws;              // 20.5 MB
    __hip_bfloat16* Vb  = X   + (size_t)N_ROWS * KST;         // 1.8 MB
    __hip_bfloat16* TPb = Vb  + (size_t)OPAD * KST;           // 15.3 MB
    __hip_bfloat16* Gt  = TPb + (size_t)OPAD * KP;            // 1.74 MB

    cvt_M<<<(OPAD * GPR + 255) / 256, 256, 0, stream>>>(TP, TPb);
    build_G<<<(KST * GPR + 255) / 256, 256, 0, stream>>>(W, Gt);
    build_X<<<(N_ROWS * (KST / 8) + 255) / 256, 256, 0, stream>>>(sk, ang, X);

    dim3 gridV(KST / 64, OPAD / 128);   // (5, 22)
    gemm_V<<<gridV, 256, 0, stream>>>(TPb, Gt, Vb);

    dim3 grid(OPAD / 128, N_ROWS / 128);   // (22, 250)
    gemm_bt<<<grid, 512, 0, stream>>>(X, Vb, out);
}

// Round 19
// 160.924 us; speedup vs baseline: 1.1834x; 1.1834x over previous
//
#include <hip/hip_runtime.h>
#include <hip/hip_bf16.h>

// Problem geometry
#define N_ROWS 32000   // Q_OUT*Q_IN*NUM_P
#define SB     12      // SCALAR_BASIS
#define FC     720     // FILTER_C
#define FD     2704    // FILTER_DIM
#define OCOLS  2704    // DIM_OUT*DIM_IN
#define OPAD   2816    // padded o (11*256)
#define ANGD   25
#define PDIM   300     // SB * ANGD
#define KST    320     // PDIM padded to 5*64 (main GEMM K)
#define NT     5       // main GEMM K tiles of 64
#define KP     2720    // FD padded to 85*32 (V-GEMM K)
#define NTV    85      // V-GEMM K tiles of 32
#define GPR    (KP/8)  // 340 groups per TPb row

typedef __attribute__((ext_vector_type(8))) short bf16x8;
typedef __attribute__((ext_vector_type(4))) float f32x4;

__device__ __forceinline__ void gload16(const void* g, void* l) {
    __builtin_amdgcn_global_load_lds(
        (const __attribute__((address_space(1))) void*)g,
        (__attribute__((address_space(3))) void*)l, 16, 0, 0);
}

__device__ __forceinline__ void decode_f(int f, int& c, int& j, int& a) {
    if (f < 144)       { c = f;                         j = 0;            a = 0;  }
    else if (f < 960)  { int t = f - 144;  c = 144 + t/3; j = t - (t/3)*3; a = 1;  }
    else if (f < 2000) { int t = f - 960;  c = 416 + t/5; j = t - (t/5)*5; a = 4;  }
    else if (f < 2560) { int t = f - 2000; c = 624 + t/7; j = t - (t/7)*7; a = 9;  }
    else               { int t = f - 2560; c = 704 + t/9; j = t - (t/9)*9; a = 16; }
}

// ---------------------------------------------------------------------------
// Kernel 1 (R14 proven): TP (2704x2704 f32) -> TPb bf16 padded (OPAD x KP).
// ---------------------------------------------------------------------------
__global__ void cvt_M(const float* __restrict__ M, __hip_bfloat16* __restrict__ out)
{
    const int g = blockIdx.x * 256 + threadIdx.x;
    if (g >= OPAD * GPR) return;
    const int o = g / GPR;
    const int k = (g - o * GPR) * 8;
    alignas(16) __hip_bfloat16 tmp[8];
    if (o < OCOLS && k + 8 <= FD) {
        const float4* p = (const float4*)(M + (size_t)o * FD + k);
        float4 x0 = p[0], x1 = p[1];
        tmp[0] = __float2bfloat16(x0.x); tmp[1] = __float2bfloat16(x0.y);
        tmp[2] = __float2bfloat16(x0.z); tmp[3] = __float2bfloat16(x0.w);
        tmp[4] = __float2bfloat16(x1.x); tmp[5] = __float2bfloat16(x1.y);
        tmp[6] = __float2bfloat16(x1.z); tmp[7] = __float2bfloat16(x1.w);
    } else {
        #pragma unroll
        for (int u = 0; u < 8; ++u) {
            float v = (o < OCOLS && k + u < FD) ? M[(size_t)o * FD + k + u] : 0.f;
            tmp[u] = __float2bfloat16(v);
        }
    }
    *(bf16x8*)(out + (size_t)o * KP + k) = *(const bf16x8*)tmp;
}

// ---------------------------------------------------------------------------
// Kernel 2 (R14 proven): Gt[p][f] = match ? W[s(p),c(f)]/sqrt12 : 0.
// ---------------------------------------------------------------------------
__global__ void build_G(const float* __restrict__ W, __hip_bfloat16* __restrict__ Gt)
{
    const int g = blockIdx.x * 256 + threadIdx.x;
    if (g >= KST * GPR) return;
    const int p  = g / GPR;
    const int f0 = (g - p * GPR) * 8;
    const int s     = p / ANGD;
    const int alpha = p - s * ANGD;
    const float inv = 0.28867513459481288f;
    alignas(16) __hip_bfloat16 tmp[8];
    #pragma unroll
    for (int u = 0; u < 8; ++u) {
        const int f = f0 + u;
        float v = 0.f;
        if (p < PDIM && f < FD) {
            int c, j, a;
            decode_f(f, c, j, a);
            if (alpha == a + j) v = W[s * FC + c] * inv;
        }
        tmp[u] = __float2bfloat16(v);
    }
    *(bf16x8*)(Gt + (size_t)p * KP + f0) = *(const bf16x8*)tmp;
}

// ---------------------------------------------------------------------------
// Kernel 3 (R14 proven): X[n, s*25+a] = sk[n,s] * ang[n,a], bf16.
// ---------------------------------------------------------------------------
__global__ void build_X(const float* __restrict__ sk,
                        const float* __restrict__ ang,
                        __hip_bfloat16* __restrict__ X)
{
    const int idx = blockIdx.x * 256 + threadIdx.x;
    if (idx >= N_ROWS * (KST / 8)) return;
    const int n  = idx / (KST / 8);
    const int p0 = (idx - n * (KST / 8)) * 8;
    const float* skn  = sk  + (size_t)n * SB;
    const float* angn = ang + (size_t)n * ANGD;
    alignas(16) __hip_bfloat16 tmp[8];
    #pragma unroll
    for (int u = 0; u < 8; ++u) {
        const int p = p0 + u;
        float v = 0.f;
        if (p < PDIM) {
            const int s = p / ANGD;
            const int a = p - s * ANGD;
            v = skn[s] * angn[a];
        }
        tmp[u] = __float2bfloat16(v);
    }
    *(bf16x8*)(X + (size_t)n * KST + p0) = *(const bf16x8*)tmp;
}

// ---------------------------------------------------------------------------
// Kernel 4 (R14 proven): V-GEMM. V[o,p] = sum_f TPb[o,f] * Gt[p,f].
// ---------------------------------------------------------------------------
__global__ __launch_bounds__(256, 4) void gemm_V(
    const __hip_bfloat16* __restrict__ A,   // TPb: (OPAD, KP)
    const __hip_bfloat16* __restrict__ B,   // Gt:  (KST, KP)
    __hip_bfloat16* __restrict__ V)         // (OPAD, KST)
{
    __shared__ __align__(1024) char lds[24576];
    char* const bufA = lds;
    char* const bufB = lds + 16384;

    const int tid  = threadIdx.x;
    const int wave = tid >> 6;
    const int lane = tid & 63;

    const int bn = blockIdx.x;         // 5 col tiles (64 p each)
    const int bm = blockIdx.y;         // 22 row tiles (128 o each)
    const size_t arow0 = (size_t)bm * 128;
    const size_t brow0 = (size_t)bn * 64;

    const int wr = wave >> 1;
    const int wc = wave & 1;

    const int lrow2 = lane >> 2;
    const int sslot = (((lane & 3) ^ (lrow2 & 3) ^ ((lane >> 4) & 3))) << 4;

    auto STAGE = [&](int t, int half) {
        char* const la = bufA + half * 8192;
        char* const lb = bufB + half * 4096;
        const char* ga = (const char*)A
            + (arow0 + (size_t)(wave * 16 + lrow2)) * (KP * 2)
            + (size_t)t * 64 + sslot;
        gload16(ga,                         la + wave * 1024);
        gload16(ga + (size_t)64 * (KP * 2), la + 4096 + wave * 1024);
        const char* gb = (const char*)B
            + (brow0 + (size_t)(wave * 16 + lrow2)) * (KP * 2)
            + (size_t)t * 64 + sslot;
        gload16(gb, lb + wave * 1024);
    };

    const int rl   = lane & 15;
    const int koct = lane >> 4;
    const int rslot = ((koct ^ (rl & 3) ^ ((rl >> 2) & 3))) << 4;

    STAGE(0, 0);
    STAGE(1, 1);
    asm volatile("s_waitcnt vmcnt(3)" ::: "memory");
    __builtin_amdgcn_s_barrier();

    f32x4 acc[4][2] = {};

    for (int t = 0; t < NTV; ++t) {
        char* const aC = bufA + (t & 1) * 8192;
        char* const bC = bufB + (t & 1) * 4096;

        bf16x8 af[4], bfr[2];
        #pragma unroll
        for (int m = 0; m < 4; ++m) {
            const int r = wr * 64 + m * 16 + rl;
            af[m] = *(const bf16x8*)(aC + r * 64 + rslot);
        }
        #pragma unroll
        for (int n = 0; n < 2; ++n) {
            const int r = wc * 32 + n * 16 + rl;
            bfr[n] = *(const bf16x8*)(bC + r * 64 + rslot);
        }
        asm volatile("s_waitcnt lgkmcnt(0)" ::: "memory");
        __builtin_amdgcn_sched_barrier(0);
        __builtin_amdgcn_s_barrier();

        if (t + 2 < NTV) STAGE(t + 2, t & 1);

        __builtin_amdgcn_s_setprio(1);
        #pragma unroll
        for (int m = 0; m < 4; ++m)
            #pragma unroll
            for (int n = 0; n < 2; ++n)
                acc[m][n] = __builtin_amdgcn_mfma_f32_16x16x32_bf16(
                    bfr[n], af[m], acc[m][n], 0, 0, 0);
        __builtin_amdgcn_s_setprio(0);
        __builtin_amdgcn_sched_barrier(0);

        if (t < NTV - 2)       asm volatile("s_waitcnt vmcnt(3)" ::: "memory");
        else if (t == NTV - 2) asm volatile("s_waitcnt vmcnt(0)" ::: "memory");
        if (t < NTV - 1) __builtin_amdgcn_s_barrier();
    }

    const int obase = (int)arow0 + wr * 64 + rl;
    const int pbase = (int)brow0 + wc * 32 + koct * 4;
    #pragma unroll
    for (int m = 0; m < 4; ++m) {
        const int orow = obase + m * 16;
        #pragma unroll
        for (int n = 0; n < 2; ++n) {
            const int p = pbase + n * 16;
            alignas(8) __hip_bfloat16 t4[4];
            t4[0] = __float2bfloat16(acc[m][n][0]);
            t4[1] = __float2bfloat16(acc[m][n][1]);
            t4[2] = __float2bfloat16(acc[m][n][2]);
            t4[3] = __float2bfloat16(acc[m][n][3]);
            *(uint2*)(V + (size_t)orow * KST + p) = *(const uint2*)t4;
        }
    }
}

// ---------------------------------------------------------------------------
// Kernel 5: main GEMM, 256x256 tile (R5-verified 8-phase structure, K=320).
// Halves fabric reads: per-tile reads 320 KB per 256 KB output (was 2.5:1
// at 128x128 -> 880 MB total; now 1.25:1 -> 440 MB). 8 waves (2M x 4N),
// per-wave 128x64, acc[8][4]. Swapped MFMA -> D^T frags. Natural block
// order (11 consecutive blocks share an A-panel). Epilogue: R14-proven
// LDS-routed full-line nt stores, 4 passes of 64 M-rows via s_c[64][260].
// ---------------------------------------------------------------------------
__global__ __launch_bounds__(512, 2) void gemm_bt(
    const __hip_bfloat16* __restrict__ A,   // X: (N_ROWS, KST)
    const __hip_bfloat16* __restrict__ B,   // V: (OPAD, KST)
    float* __restrict__ C)
{
    __shared__ __align__(1024) char lds[131072];
    char* const ldsA = lds;           // 2 buf x 2 half x 16384 B
    char* const ldsB = lds + 65536;
    float* const s_c = (float*)lds;   // epilogue alias: [64][260] f32 (66560 B)

    const int tid  = threadIdx.x;
    const int wave = tid >> 6;
    const int lane = tid & 63;

    const int wgid = blockIdx.x;       // 0..1374; natural order: 11 per bm
    const int bm = wgid / 11;
    const int bn = wgid - bm * 11;
    const size_t arow0 = (size_t)bm * 256;
    const size_t brow0 = (size_t)bn * 256;

    const int wr = wave >> 2;   // 0..1 (M)
    const int wc = wave & 3;    // 0..3 (o)

    // staging lane constants (LDS linear dest; global source pre-swizzled)
    const int lrow  = lane >> 3;
    const int lslot = ((lane & 7) ^ (lrow & 7)) << 4;

    auto STAGE = [&](const char* gbase, size_t growbase, int tile, char* lbase) {
        const char* g0 = gbase + (growbase + (size_t)(wave * 8 + lrow)) * (KST * 2)
                               + (size_t)tile * 128 + lslot;
        gload16(g0,                          lbase + wave * 1024);
        gload16(g0 + (size_t)64 * (KST * 2), lbase + 8192 + wave * 1024);
    };

    // reader lane constants
    const int rl   = lane & 15;
    const int koct = lane >> 4;
    const int sK0 = ((0 * 4 + koct) ^ (lane & 7)) << 4;
    const int sK1 = ((1 * 4 + koct) ^ (lane & 7)) << 4;
    const int arow = wr * 64 + rl;
    const int brow = (wc & 1) * 64 + rl;
    const int bhalf = wc >> 1;

    // prologue: tile0 {B0,B1,A0,A1}, tile1 {B0,B1,A0}  (7 half-tiles)
    STAGE((const char*)B, brow0 + 0,   0, ldsB + 0);
    STAGE((const char*)B, brow0 + 128, 0, ldsB + 16384);
    STAGE((const char*)A, arow0 + 0,   0, ldsA + 0);
    STAGE((const char*)A, arow0 + 128, 0, ldsA + 16384);
    STAGE((const char*)B, brow0 + 0,   1, ldsB + 32768);
    STAGE((const char*)B, brow0 + 128, 1, ldsB + 32768 + 16384);
    STAGE((const char*)A, arow0 + 0,   1, ldsA + 32768);
    asm volatile("s_waitcnt vmcnt(6)" ::: "memory");
    __builtin_amdgcn_s_barrier();

    f32x4 acc[8][4] = {};   // [q*2+m][n]; D^T frags: row=o, col=M

    for (int t = 0; t < NT; ++t) {
        char* const aB  = ldsA + (t & 1) * 32768;
        char* const bB  = ldsB + (t & 1) * 32768;
        char* const aBn = ldsA + ((t + 1) & 1) * 32768;

        bf16x8 bfr[4][2];
        #pragma unroll
        for (int q = 0; q < 4; ++q) {
            asm volatile("" ::: "memory");
            __builtin_amdgcn_sched_barrier(0);

            bf16x8 af[2][2];
            char* ah = aB + (q >> 1) * 16384;
            #pragma unroll
            for (int m = 0; m < 2; ++m) {
                const int r = arow + (q & 1) * 32 + m * 16;
                af[m][0] = *(const bf16x8*)(ah + r * 128 + sK0);
                af[m][1] = *(const bf16x8*)(ah + r * 128 + sK1);
            }
            if (q == 0) {
                char* bh = bB + bhalf * 16384;
                #pragma unroll
                for (int n = 0; n < 4; ++n) {
                    bfr[n][0] = *(const bf16x8*)(bh + (brow + n * 16) * 128 + sK0);
                    bfr[n][1] = *(const bf16x8*)(bh + (brow + n * 16) * 128 + sK1);
                }
            }

            if (q == 0 && t + 1 < NT) STAGE((const char*)A, arow0 + 128, t + 1, aBn + 16384);
            if (q == 1 && t + 2 < NT) STAGE((const char*)B, brow0 + 0,   t + 2, bB + 0);
            if (q == 2 && t + 2 < NT) STAGE((const char*)B, brow0 + 128, t + 2, bB + 16384);
            if (q == 3 && t + 2 < NT) STAGE((const char*)A, arow0 + 0,   t + 2, aB + 0);

            __builtin_amdgcn_s_barrier();
            asm volatile("s_waitcnt lgkmcnt(0)" ::: "memory");
            __builtin_amdgcn_sched_barrier(0);

            __builtin_amdgcn_s_setprio(1);
            #pragma unroll
            for (int ks = 0; ks < 2; ++ks)
                #pragma unroll
                for (int m = 0; m < 2; ++m)
                    #pragma unroll
                    for (int n = 0; n < 4; ++n)
                        acc[q * 2 + m][n] = __builtin_amdgcn_mfma_f32_16x16x32_bf16(
                            bfr[n][ks], af[m][ks], acc[q * 2 + m][n], 0, 0, 0);
            __builtin_amdgcn_s_setprio(0);
            __builtin_amdgcn_sched_barrier(0);

            if (q == 3 && t + 1 < NT) {
                if (t + 1 == NT - 1) asm volatile("s_waitcnt vmcnt(0)" ::: "memory");
                else                 asm volatile("s_waitcnt vmcnt(6)" ::: "memory");
            }
            __builtin_amdgcn_s_barrier();
        }
    }

    // ---- epilogue: 4 passes of 64 M-rows through s_c, full-line nt stores.
    // M = arow0 + (q>>1)*128 + wr*64 + (q&1)*32 + m*16 + rl
    // o = brow0 + wc*64 + n*16 + koct*4 (+reg r)
    #pragma unroll
    for (int h = 0; h < 4; ++h) {
        __syncthreads();
        if (wr == (h & 1)) {
            const int qh = (h >> 1) * 2;
            #pragma unroll
            for (int qq = 0; qq < 2; ++qq)
                #pragma unroll
                for (int m = 0; m < 2; ++m) {
                    const int row_l = qq * 32 + m * 16 + rl;   // 0..63
                    #pragma unroll
                    for (int n = 0; n < 4; ++n) {
                        const int col = wc * 64 + n * 16 + koct * 4;  // 0..252
                        *(f32x4*)&s_c[row_l * 260 + col] = acc[(qh + qq) * 2 + m][n];
                    }
                }
        }
        __syncthreads();
        // readback: 64 rows x 64 f32x4-groups; wave-row = 1 KB contiguous
        #pragma unroll
        for (int rr = 0; rr < 8; ++rr) {
            const int idx = rr * 512 + tid;
            const int row = idx >> 6;          // wave-uniform
            const int g4  = (idx & 63) * 4;    // lane*4
            if ((int)brow0 + g4 < OCOLS) {
                const f32x4 v = *(const f32x4*)&s_c[row * 260 + g4];
                __builtin_nontemporal_store(v,
                    (f32x4*)(C + (size_t)(arow0 + h * 64 + row) * OCOLS + brow0 + g4));
            }
        }
    }
}

// ---------------------------------------------------------------------------
extern "C" void kernel_launch(void* const* d_in, const int* in_sizes, int n_in,
                              void* d_out, int out_size, void* d_ws, size_t ws_size,
                              hipStream_t stream)
{
    const float* sk  = (const float*)d_in[0];   // (16,16,125,12)
    const float* ang = (const float*)d_in[1];   // (32000,25)
    const float* W   = (const float*)d_in[2];   // (12,720)
    const float* TP  = (const float*)d_in[3];   // (2704,2704)
    float* out = (float*)d_out;                 // (32000,2704)

    __hip_bfloat16* X   = (__hip_bfloat16*)d_ws;              // 20.5 MB
    __hip_bfloat16* Vb  = X   + (size_t)N_ROWS * KST;         // 1.8 MB
    __hip_bfloat16* TPb = Vb  + (size_t)OPAD * KST;           // 15.3 MB
    __hip_bfloat16* Gt  = TPb + (size_t)OPAD * KP;            // 1.74 MB

    cvt_M<<<(OPAD * GPR + 255) / 256, 256, 0, stream>>>(TP, TPb);
    build_G<<<(KST * GPR + 255) / 256, 256, 0, stream>>>(W, Gt);
    build_X<<<(N_ROWS * (KST / 8) + 255) / 256, 256, 0, stream>>>(sk, ang, X);

    dim3 gridV(KST / 64, OPAD / 128);   // (5, 22)
    gemm_V<<<gridV, 256, 0, stream>>>(TPb, Gt, Vb);

    gemm_bt<<<125 * 11, 512, 0, stream>>>(X, Vb, out);
}

// Round 20
// 136.133 us; speedup vs baseline: 1.3989x; 1.1821x over previous
//
#include <hip/hip_runtime.h>
#include <hip/hip_bf16.h>

// Problem geometry
#define N_ROWS 32000   // Q_OUT*Q_IN*NUM_P
#define SB     12      // SCALAR_BASIS
#define FC     720     // FILTER_C
#define FD     2704    // FILTER_DIM
#define OCOLS  2704    // DIM_OUT*DIM_IN
#define OPAD   2816    // padded o (22*128)
#define ANGD   25
#define PDIM   300     // SB * ANGD
#define KST    320     // PDIM padded to 5*64 (main GEMM K)
#define NT     5       // main GEMM K tiles of 64
#define KP     2720    // FD padded to 85*32 (V-GEMM K)
#define NTV    85      // V-GEMM K tiles of 32
#define GPR    (KP/8)  // 340 groups per TPb row

// merged-prep block ranges
#define NB_CVT 3740    // OPAD*GPR/256
#define NB_G   425     // KST*GPR/256
#define NB_X   5000    // N_ROWS*(KST/8)/256

typedef __attribute__((ext_vector_type(8))) short bf16x8;
typedef __attribute__((ext_vector_type(4))) float f32x4;

__device__ __forceinline__ void gload16(const void* g, void* l) {
    __builtin_amdgcn_global_load_lds(
        (const __attribute__((address_space(1))) void*)g,
        (__attribute__((address_space(3))) void*)l, 16, 0, 0);
}

__device__ __forceinline__ void decode_f(int f, int& c, int& j, int& a) {
    if (f < 144)       { c = f;                         j = 0;            a = 0;  }
    else if (f < 960)  { int t = f - 144;  c = 144 + t/3; j = t - (t/3)*3; a = 1;  }
    else if (f < 2000) { int t = f - 960;  c = 416 + t/5; j = t - (t/5)*5; a = 4;  }
    else if (f < 2560) { int t = f - 2000; c = 624 + t/7; j = t - (t/7)*7; a = 9;  }
    else               { int t = f - 2560; c = 704 + t/9; j = t - (t/9)*9; a = 16; }
}

// ---------------------------------------------------------------------------
// Merged prep (no LDS in any branch -> full occupancy everywhere):
//  blocks [0, NB_CVT):            TP f32 -> TPb bf16 padded (OPAD x KP)
//  blocks [NB_CVT, NB_CVT+NB_G):  Gt[p][f] = match ? W[s,c]/sqrt12 : 0
//  blocks [.., +NB_X):            X[n, s*25+a] = sk[n,s]*ang[n,a]
// Bodies byte-equivalent to R14's cvt_M / build_G / build_X.
// ---------------------------------------------------------------------------
__global__ __launch_bounds__(256) void prep(
    const float* __restrict__ TP,
    const float* __restrict__ W,
    const float* __restrict__ sk,
    const float* __restrict__ ang,
    __hip_bfloat16* __restrict__ TPb,
    __hip_bfloat16* __restrict__ Gt,
    __hip_bfloat16* __restrict__ X)
{
    const int b = blockIdx.x;
    if (b < NB_CVT) {
        const int g = b * 256 + threadIdx.x;
        if (g >= OPAD * GPR) return;
        const int o = g / GPR;
        const int k = (g - o * GPR) * 8;
        alignas(16) __hip_bfloat16 tmp[8];
        if (o < OCOLS && k + 8 <= FD) {
            const float4* p = (const float4*)(TP + (size_t)o * FD + k);
            float4 x0 = p[0], x1 = p[1];
            tmp[0] = __float2bfloat16(x0.x); tmp[1] = __float2bfloat16(x0.y);
            tmp[2] = __float2bfloat16(x0.z); tmp[3] = __float2bfloat16(x0.w);
            tmp[4] = __float2bfloat16(x1.x); tmp[5] = __float2bfloat16(x1.y);
            tmp[6] = __float2bfloat16(x1.z); tmp[7] = __float2bfloat16(x1.w);
        } else {
            #pragma unroll
            for (int u = 0; u < 8; ++u) {
                float v = (o < OCOLS && k + u < FD) ? TP[(size_t)o * FD + k + u] : 0.f;
                tmp[u] = __float2bfloat16(v);
            }
        }
        *(bf16x8*)(TPb + (size_t)o * KP + k) = *(const bf16x8*)tmp;
    } else if (b < NB_CVT + NB_G) {
        const int g = (b - NB_CVT) * 256 + threadIdx.x;
        if (g >= KST * GPR) return;
        const int p  = g / GPR;
        const int f0 = (g - p * GPR) * 8;
        const int s     = p / ANGD;
        const int alpha = p - s * ANGD;
        const float inv = 0.28867513459481288f;
        alignas(16) __hip_bfloat16 tmp[8];
        #pragma unroll
        for (int u = 0; u < 8; ++u) {
            const int f = f0 + u;
            float v = 0.f;
            if (p < PDIM && f < FD) {
                int c, j, a;
                decode_f(f, c, j, a);
                if (alpha == a + j) v = W[s * FC + c] * inv;
            }
            tmp[u] = __float2bfloat16(v);
        }
        *(bf16x8*)(Gt + (size_t)p * KP + f0) = *(const bf16x8*)tmp;
    } else {
        const int idx = (b - NB_CVT - NB_G) * 256 + threadIdx.x;
        if (idx >= N_ROWS * (KST / 8)) return;
        const int n  = idx / (KST / 8);
        const int p0 = (idx - n * (KST / 8)) * 8;
        const float* skn  = sk  + (size_t)n * SB;
        const float* angn = ang + (size_t)n * ANGD;
        alignas(16) __hip_bfloat16 tmp[8];
        #pragma unroll
        for (int u = 0; u < 8; ++u) {
            const int p = p0 + u;
            float v = 0.f;
            if (p < PDIM) {
                const int s = p / ANGD;
                const int a = p - s * ANGD;
                v = skn[s] * angn[a];
            }
            tmp[u] = __float2bfloat16(v);
        }
        *(bf16x8*)(X + (size_t)n * KST + p0) = *(const bf16x8*)tmp;
    }
}

// ---------------------------------------------------------------------------
// Kernel 4 (R14 proven, byte-identical): V-GEMM. V[o,p] = sum_f TPb[o,f]*Gt[p,f].
// ---------------------------------------------------------------------------
__global__ __launch_bounds__(256, 4) void gemm_V(
    const __hip_bfloat16* __restrict__ A,   // TPb: (OPAD, KP)
    const __hip_bfloat16* __restrict__ B,   // Gt:  (KST, KP)
    __hip_bfloat16* __restrict__ V)         // (OPAD, KST)
{
    __shared__ __align__(1024) char lds[24576];
    char* const bufA = lds;
    char* const bufB = lds + 16384;

    const int tid  = threadIdx.x;
    const int wave = tid >> 6;
    const int lane = tid & 63;

    const int bn = blockIdx.x;         // 5 col tiles (64 p each)
    const int bm = blockIdx.y;         // 22 row tiles (128 o each)
    const size_t arow0 = (size_t)bm * 128;
    const size_t brow0 = (size_t)bn * 64;

    const int wr = wave >> 1;
    const int wc = wave & 1;

    const int lrow2 = lane >> 2;
    const int sslot = (((lane & 3) ^ (lrow2 & 3) ^ ((lane >> 4) & 3))) << 4;

    auto STAGE = [&](int t, int half) {
        char* const la = bufA + half * 8192;
        char* const lb = bufB + half * 4096;
        const char* ga = (const char*)A
            + (arow0 + (size_t)(wave * 16 + lrow2)) * (KP * 2)
            + (size_t)t * 64 + sslot;
        gload16(ga,                         la + wave * 1024);
        gload16(ga + (size_t)64 * (KP * 2), la + 4096 + wave * 1024);
        const char* gb = (const char*)B
            + (brow0 + (size_t)(wave * 16 + lrow2)) * (KP * 2)
            + (size_t)t * 64 + sslot;
        gload16(gb, lb + wave * 1024);
    };

    const int rl   = lane & 15;
    const int koct = lane >> 4;
    const int rslot = ((koct ^ (rl & 3) ^ ((rl >> 2) & 3))) << 4;

    STAGE(0, 0);
    STAGE(1, 1);
    asm volatile("s_waitcnt vmcnt(3)" ::: "memory");
    __builtin_amdgcn_s_barrier();

    f32x4 acc[4][2] = {};

    for (int t = 0; t < NTV; ++t) {
        char* const aC = bufA + (t & 1) * 8192;
        char* const bC = bufB + (t & 1) * 4096;

        bf16x8 af[4], bfr[2];
        #pragma unroll
        for (int m = 0; m < 4; ++m) {
            const int r = wr * 64 + m * 16 + rl;
            af[m] = *(const bf16x8*)(aC + r * 64 + rslot);
        }
        #pragma unroll
        for (int n = 0; n < 2; ++n) {
            const int r = wc * 32 + n * 16 + rl;
            bfr[n] = *(const bf16x8*)(bC + r * 64 + rslot);
        }
        asm volatile("s_waitcnt lgkmcnt(0)" ::: "memory");
        __builtin_amdgcn_sched_barrier(0);
        __builtin_amdgcn_s_barrier();

        if (t + 2 < NTV) STAGE(t + 2, t & 1);

        __builtin_amdgcn_s_setprio(1);
        #pragma unroll
        for (int m = 0; m < 4; ++m)
            #pragma unroll
            for (int n = 0; n < 2; ++n)
                acc[m][n] = __builtin_amdgcn_mfma_f32_16x16x32_bf16(
                    bfr[n], af[m], acc[m][n], 0, 0, 0);
        __builtin_amdgcn_s_setprio(0);
        __builtin_amdgcn_sched_barrier(0);

        if (t < NTV - 2)       asm volatile("s_waitcnt vmcnt(3)" ::: "memory");
        else if (t == NTV - 2) asm volatile("s_waitcnt vmcnt(0)" ::: "memory");
        if (t < NTV - 1) __builtin_amdgcn_s_barrier();
    }

    const int obase = (int)arow0 + wr * 64 + rl;
    const int pbase = (int)brow0 + wc * 32 + koct * 4;
    #pragma unroll
    for (int m = 0; m < 4; ++m) {
        const int orow = obase + m * 16;
        #pragma unroll
        for (int n = 0; n < 2; ++n) {
            const int p = pbase + n * 16;
            alignas(8) __hip_bfloat16 t4[4];
            t4[0] = __float2bfloat16(acc[m][n][0]);
            t4[1] = __float2bfloat16(acc[m][n][1]);
            t4[2] = __float2bfloat16(acc[m][n][2]);
            t4[3] = __float2bfloat16(acc[m][n][3]);
            *(uint2*)(V + (size_t)orow * KST + p) = *(const uint2*)t4;
        }
    }
}

// ---------------------------------------------------------------------------
// Kernel 5 (R14 proven, byte-identical): main GEMM 128x128, K=320.
// A+B staged via swizzled gload_lds dbuf; swapped MFMA -> D^T frags;
// LDS-routed two-pass full-line nt-store epilogue.
// ---------------------------------------------------------------------------
__global__ __launch_bounds__(512, 4) void gemm_bt(
    const __hip_bfloat16* __restrict__ A,   // X: (N_ROWS, KST)
    const __hip_bfloat16* __restrict__ B,   // V: (OPAD, KST)
    float* __restrict__ C)
{
    __shared__ __align__(1024) char lds[65536];
    char* const bufA = lds;            // 2 x 16384 B
    char* const bufB = lds + 32768;    // 2 x 16384 B
    float* const s_c = (float*)lds;    // epilogue alias: [64][132] f32

    const int tid  = threadIdx.x;
    const int wave = tid >> 6;
    const int lane = tid & 63;

    const int bn = blockIdx.x;         // 22 col tiles
    const int bm = blockIdx.y;         // 250 row tiles
    const size_t arow0 = (size_t)bm * 128;
    const size_t brow0 = (size_t)bn * 128;

    const int wr = wave >> 2;
    const int wc = wave & 3;

    const int lrow  = lane >> 3;
    const int lslot = ((lane & 7) ^ (lrow & 7)) << 4;

    auto STAGE = [&](const char* gbase, size_t growbase, int t, char* lbase) {
        const char* g0 = gbase + (growbase + (size_t)(wave * 8 + lrow)) * (KST * 2)
                               + (size_t)t * 128 + lslot;
        gload16(g0,                          lbase + wave * 1024);
        gload16(g0 + (size_t)64 * (KST * 2), lbase + 8192 + wave * 1024);
    };

    const int rl   = lane & 15;
    const int koct = lane >> 4;
    const int sK0 = ((0 * 4 + koct) ^ (lane & 7)) << 4;
    const int sK1 = ((1 * 4 + koct) ^ (lane & 7)) << 4;

    STAGE((const char*)A, arow0, 0, bufA + 0);
    STAGE((const char*)B, brow0, 0, bufB + 0);
    STAGE((const char*)A, arow0, 1, bufA + 16384);
    STAGE((const char*)B, brow0, 1, bufB + 16384);
    asm volatile("s_waitcnt vmcnt(4)" ::: "memory");
    __builtin_amdgcn_s_barrier();

    f32x4 acc[4][2] = {};

    for (int t = 0; t < NT; ++t) {
        char* const aC = bufA + (t & 1) * 16384;
        char* const bC = bufB + (t & 1) * 16384;

        bf16x8 af[4][2], bfr[2][2];
        #pragma unroll
        for (int m = 0; m < 4; ++m) {
            const int r = wr * 64 + m * 16 + rl;
            af[m][0] = *(const bf16x8*)(aC + r * 128 + sK0);
            af[m][1] = *(const bf16x8*)(aC + r * 128 + sK1);
        }
        #pragma unroll
        for (int n = 0; n < 2; ++n) {
            const int r = wc * 32 + n * 16 + rl;
            bfr[n][0] = *(const bf16x8*)(bC + r * 128 + sK0);
            bfr[n][1] = *(const bf16x8*)(bC + r * 128 + sK1);
        }
        asm volatile("s_waitcnt lgkmcnt(0)" ::: "memory");
        __builtin_amdgcn_sched_barrier(0);
        __builtin_amdgcn_s_barrier();

        if (t + 2 < NT) {
            STAGE((const char*)A, arow0, t + 2, aC);
            STAGE((const char*)B, brow0, t + 2, bC);
        }

        __builtin_amdgcn_s_setprio(1);
        #pragma unroll
        for (int ks = 0; ks < 2; ++ks)
            #pragma unroll
            for (int m = 0; m < 4; ++m)
                #pragma unroll
                for (int n = 0; n < 2; ++n)
                    acc[m][n] = __builtin_amdgcn_mfma_f32_16x16x32_bf16(
                        bfr[n][ks], af[m][ks], acc[m][n], 0, 0, 0);
        __builtin_amdgcn_s_setprio(0);
        __builtin_amdgcn_sched_barrier(0);

        if (t < NT - 2)       asm volatile("s_waitcnt vmcnt(4)" ::: "memory");
        else if (t == NT - 2) asm volatile("s_waitcnt vmcnt(0)" ::: "memory");
        if (t < NT - 1) __builtin_amdgcn_s_barrier();
    }

    #pragma unroll
    for (int h = 0; h < 2; ++h) {
        __syncthreads();
        if (wr == h) {
            #pragma unroll
            for (int m = 0; m < 4; ++m) {
                const int row_l = m * 16 + rl;
                #pragma unroll
                for (int n = 0; n < 2; ++n) {
                    const int col = wc * 32 + n * 16 + koct * 4;
                    *(f32x4*)&s_c[row_l * 132 + col] = acc[m][n];
                }
            }
        }
        __syncthreads();
        #pragma unroll
        for (int rr = 0; rr < 4; ++rr) {
            const int idx  = rr * 512 + tid;
            const int row  = idx >> 5;
            const int g4   = (idx & 31) * 4;
            if ((int)brow0 + g4 < OCOLS) {
                const f32x4 v = *(const f32x4*)&s_c[row * 132 + g4];
                __builtin_nontemporal_store(v,
                    (f32x4*)(C + (size_t)(arow0 + h * 64 + row) * OCOLS + brow0 + g4));
            }
        }
    }
}

// ---------------------------------------------------------------------------
extern "C" void kernel_launch(void* const* d_in, const int* in_sizes, int n_in,
                              void* d_out, int out_size, void* d_ws, size_t ws_size,
                              hipStream_t stream)
{
    const float* sk  = (const float*)d_in[0];   // (16,16,125,12)
    const float* ang = (const float*)d_in[1];   // (32000,25)
    const float* W   = (const float*)d_in[2];   // (12,720)
    const float* TP  = (const float*)d_in[3];   // (2704,2704)
    float* out = (float*)d_out;                 // (32000,2704)

    __hip_bfloat16* X   = (__hip_bfloat16*)d_ws;              // 20.5 MB
    __hip_bfloat16* Vb  = X   + (size_t)N_ROWS * KST;         // 1.8 MB
    __hip_bfloat16* TPb = Vb  + (size_t)OPAD * KST;           // 15.3 MB
    __hip_bfloat16* Gt  = TPb + (size_t)OPAD * KP;            // 1.74 MB

    prep<<<NB_CVT + NB_G + NB_X, 256, 0, stream>>>(TP, W, sk, ang, TPb, Gt, X);

    dim3 gridV(KST / 64, OPAD / 128);   // (5, 22)
    gemm_V<<<gridV, 256, 0, stream>>>(TPb, Gt, Vb);

    dim3 grid(OPAD / 128, N_ROWS / 128);   // (22, 250)
    gemm_bt<<<grid, 512, 0, stream>>>(X, Vb, out);
}

// Round 21
// 129.162 us; speedup vs baseline: 1.4744x; 1.0540x over previous
//
#include <hip/hip_runtime.h>
#include <hip/hip_bf16.h>

// Problem geometry
#define N_ROWS 32000   // Q_OUT*Q_IN*NUM_P
#define SB     12      // SCALAR_BASIS
#define FC     720     // FILTER_C
#define FD     2704    // FILTER_DIM
#define OCOLS  2704    // DIM_OUT*DIM_IN
#define OPAD   2816    // padded o (22*128)
#define ANGD   25
#define PDIM   300     // SB * ANGD
#define KST    320     // PDIM padded to 5*64 (main GEMM K)
#define NT     5       // main GEMM K tiles of 64
#define KP     2720    // FD padded to 85*32 (V-GEMM K)
#define NTV    85      // V-GEMM K tiles of 32
#define GPR    (KP/8)  // 340 groups per TPb row

// launch-1 block ranges (cvt_M + build_G)
#define NB_CVT 3740    // OPAD*GPR/256
#define NB_G   425     // KST*GPR/256
// launch-2 block ranges (gemm_V + build_X)
#define NBV    110     // 5 * 22 V-GEMM tiles
#define NB_X   5000    // N_ROWS*(KST/8)/256

typedef __attribute__((ext_vector_type(8))) short bf16x8;
typedef __attribute__((ext_vector_type(4))) float f32x4;

__device__ __forceinline__ void gload16(const void* g, void* l) {
    __builtin_amdgcn_global_load_lds(
        (const __attribute__((address_space(1))) void*)g,
        (__attribute__((address_space(3))) void*)l, 16, 0, 0);
}

__device__ __forceinline__ void decode_f(int f, int& c, int& j, int& a) {
    if (f < 144)       { c = f;                         j = 0;            a = 0;  }
    else if (f < 960)  { int t = f - 144;  c = 144 + t/3; j = t - (t/3)*3; a = 1;  }
    else if (f < 2000) { int t = f - 960;  c = 416 + t/5; j = t - (t/5)*5; a = 4;  }
    else if (f < 2560) { int t = f - 2000; c = 624 + t/7; j = t - (t/7)*7; a = 9;  }
    else               { int t = f - 2560; c = 704 + t/9; j = t - (t/9)*9; a = 16; }
}

// ---------------------------------------------------------------------------
// Launch 1: cvt_M + build_G merged (R20 bodies, byte-identical).
// ---------------------------------------------------------------------------
__global__ __launch_bounds__(256) void prep1(
    const float* __restrict__ TP,
    const float* __restrict__ W,
    __hip_bfloat16* __restrict__ TPb,
    __hip_bfloat16* __restrict__ Gt)
{
    const int b = blockIdx.x;
    if (b < NB_CVT) {
        const int g = b * 256 + threadIdx.x;
        if (g >= OPAD * GPR) return;
        const int o = g / GPR;
        const int k = (g - o * GPR) * 8;
        alignas(16) __hip_bfloat16 tmp[8];
        if (o < OCOLS && k + 8 <= FD) {
            const float4* p = (const float4*)(TP + (size_t)o * FD + k);
            float4 x0 = p[0], x1 = p[1];
            tmp[0] = __float2bfloat16(x0.x); tmp[1] = __float2bfloat16(x0.y);
            tmp[2] = __float2bfloat16(x0.z); tmp[3] = __float2bfloat16(x0.w);
            tmp[4] = __float2bfloat16(x1.x); tmp[5] = __float2bfloat16(x1.y);
            tmp[6] = __float2bfloat16(x1.z); tmp[7] = __float2bfloat16(x1.w);
        } else {
            #pragma unroll
            for (int u = 0; u < 8; ++u) {
                float v = (o < OCOLS && k + u < FD) ? TP[(size_t)o * FD + k + u] : 0.f;
                tmp[u] = __float2bfloat16(v);
            }
        }
        *(bf16x8*)(TPb + (size_t)o * KP + k) = *(const bf16x8*)tmp;
    } else {
        const int g = (b - NB_CVT) * 256 + threadIdx.x;
        if (g >= KST * GPR) return;
        const int p  = g / GPR;
        const int f0 = (g - p * GPR) * 8;
        const int s     = p / ANGD;
        const int alpha = p - s * ANGD;
        const float inv = 0.28867513459481288f;
        alignas(16) __hip_bfloat16 tmp[8];
        #pragma unroll
        for (int u = 0; u < 8; ++u) {
            const int f = f0 + u;
            float v = 0.f;
            if (p < PDIM && f < FD) {
                int c, j, a;
                decode_f(f, c, j, a);
                if (alpha == a + j) v = W[s * FC + c] * inv;
            }
            tmp[u] = __float2bfloat16(v);
        }
        *(bf16x8*)(Gt + (size_t)p * KP + f0) = *(const bf16x8*)tmp;
    }
}

// ---------------------------------------------------------------------------
// Launch 2: fused gemm_V (blocks [0,NBV), R14/R20 body with flattened grid)
// + build_X (blocks [NBV, NBV+NB_X), R20 body). gemm_V blocks first so the
// 110 long blocks occupy CUs while 5000 short build_X blocks stream through
// the remaining CUs concurrently (they are mutually independent).
// ---------------------------------------------------------------------------
__global__ __launch_bounds__(256, 4) void fused_V_X(
    const __hip_bfloat16* __restrict__ A,   // TPb: (OPAD, KP)
    const __hip_bfloat16* __restrict__ B,   // Gt:  (KST, KP)
    __hip_bfloat16* __restrict__ V,         // (OPAD, KST)
    const float* __restrict__ sk,
    const float* __restrict__ ang,
    __hip_bfloat16* __restrict__ X)
{
    __shared__ __align__(1024) char lds[24576];

    if (blockIdx.x >= NBV) {
        // ---- build_X branch (no LDS use) ----
        const int idx = (blockIdx.x - NBV) * 256 + threadIdx.x;
        if (idx >= N_ROWS * (KST / 8)) return;
        const int n  = idx / (KST / 8);
        const int p0 = (idx - n * (KST / 8)) * 8;
        const float* skn  = sk  + (size_t)n * SB;
        const float* angn = ang + (size_t)n * ANGD;
        alignas(16) __hip_bfloat16 tmp[8];
        #pragma unroll
        for (int u = 0; u < 8; ++u) {
            const int p = p0 + u;
            float v = 0.f;
            if (p < PDIM) {
                const int s = p / ANGD;
                const int a = p - s * ANGD;
                v = skn[s] * angn[a];
            }
            tmp[u] = __float2bfloat16(v);
        }
        *(bf16x8*)(X + (size_t)n * KST + p0) = *(const bf16x8*)tmp;
        return;
    }

    // ---- gemm_V branch (R20 body; bn = id%5, bm = id/5) ----
    char* const bufA = lds;
    char* const bufB = lds + 16384;

    const int tid  = threadIdx.x;
    const int wave = tid >> 6;
    const int lane = tid & 63;

    const int id = blockIdx.x;
    const int bn = id % 5;             // 5 col tiles (64 p each)
    const int bm = id / 5;             // 22 row tiles (128 o each)
    const size_t arow0 = (size_t)bm * 128;
    const size_t brow0 = (size_t)bn * 64;

    const int wr = wave >> 1;
    const int wc = wave & 1;

    const int lrow2 = lane >> 2;
    const int sslot = (((lane & 3) ^ (lrow2 & 3) ^ ((lane >> 4) & 3))) << 4;

    auto STAGE = [&](int t, int half) {
        char* const la = bufA + half * 8192;
        char* const lb = bufB + half * 4096;
        const char* ga = (const char*)A
            + (arow0 + (size_t)(wave * 16 + lrow2)) * (KP * 2)
            + (size_t)t * 64 + sslot;
        gload16(ga,                         la + wave * 1024);
        gload16(ga + (size_t)64 * (KP * 2), la + 4096 + wave * 1024);
        const char* gb = (const char*)B
            + (brow0 + (size_t)(wave * 16 + lrow2)) * (KP * 2)
            + (size_t)t * 64 + sslot;
        gload16(gb, lb + wave * 1024);
    };

    const int rl   = lane & 15;
    const int koct = lane >> 4;
    const int rslot = ((koct ^ (rl & 3) ^ ((rl >> 2) & 3))) << 4;

    STAGE(0, 0);
    STAGE(1, 1);
    asm volatile("s_waitcnt vmcnt(3)" ::: "memory");
    __builtin_amdgcn_s_barrier();

    f32x4 acc[4][2] = {};

    for (int t = 0; t < NTV; ++t) {
        char* const aC = bufA + (t & 1) * 8192;
        char* const bC = bufB + (t & 1) * 4096;

        bf16x8 af[4], bfr[2];
        #pragma unroll
        for (int m = 0; m < 4; ++m) {
            const int r = wr * 64 + m * 16 + rl;
            af[m] = *(const bf16x8*)(aC + r * 64 + rslot);
        }
        #pragma unroll
        for (int n = 0; n < 2; ++n) {
            const int r = wc * 32 + n * 16 + rl;
            bfr[n] = *(const bf16x8*)(bC + r * 64 + rslot);
        }
        asm volatile("s_waitcnt lgkmcnt(0)" ::: "memory");
        __builtin_amdgcn_sched_barrier(0);
        __builtin_amdgcn_s_barrier();

        if (t + 2 < NTV) STAGE(t + 2, t & 1);

        __builtin_amdgcn_s_setprio(1);
        #pragma unroll
        for (int m = 0; m < 4; ++m)
            #pragma unroll
            for (int n = 0; n < 2; ++n)
                acc[m][n] = __builtin_amdgcn_mfma_f32_16x16x32_bf16(
                    bfr[n], af[m], acc[m][n], 0, 0, 0);
        __builtin_amdgcn_s_setprio(0);
        __builtin_amdgcn_sched_barrier(0);

        if (t < NTV - 2)       asm volatile("s_waitcnt vmcnt(3)" ::: "memory");
        else if (t == NTV - 2) asm volatile("s_waitcnt vmcnt(0)" ::: "memory");
        if (t < NTV - 1) __builtin_amdgcn_s_barrier();
    }

    const int obase = (int)arow0 + wr * 64 + rl;
    const int pbase = (int)brow0 + wc * 32 + koct * 4;
    #pragma unroll
    for (int m = 0; m < 4; ++m) {
        const int orow = obase + m * 16;
        #pragma unroll
        for (int n = 0; n < 2; ++n) {
            const int p = pbase + n * 16;
            alignas(8) __hip_bfloat16 t4[4];
            t4[0] = __float2bfloat16(acc[m][n][0]);
            t4[1] = __float2bfloat16(acc[m][n][1]);
            t4[2] = __float2bfloat16(acc[m][n][2]);
            t4[3] = __float2bfloat16(acc[m][n][3]);
            *(uint2*)(V + (size_t)orow * KST + p) = *(const uint2*)t4;
        }
    }
}

// ---------------------------------------------------------------------------
// Kernel 5 (R14/R20 proven, byte-identical): main GEMM 128x128, K=320.
// ---------------------------------------------------------------------------
__global__ __launch_bounds__(512, 4) void gemm_bt(
    const __hip_bfloat16* __restrict__ A,   // X: (N_ROWS, KST)
    const __hip_bfloat16* __restrict__ B,   // V: (OPAD, KST)
    float* __restrict__ C)
{
    __shared__ __align__(1024) char lds[65536];
    char* const bufA = lds;            // 2 x 16384 B
    char* const bufB = lds + 32768;    // 2 x 16384 B
    float* const s_c = (float*)lds;    // epilogue alias: [64][132] f32

    const int tid  = threadIdx.x;
    const int wave = tid >> 6;
    const int lane = tid & 63;

    const int bn = blockIdx.x;         // 22 col tiles
    const int bm = blockIdx.y;         // 250 row tiles
    const size_t arow0 = (size_t)bm * 128;
    const size_t brow0 = (size_t)bn * 128;

    const int wr = wave >> 2;
    const int wc = wave & 3;

    const int lrow  = lane >> 3;
    const int lslot = ((lane & 7) ^ (lrow & 7)) << 4;

    auto STAGE = [&](const char* gbase, size_t growbase, int t, char* lbase) {
        const char* g0 = gbase + (growbase + (size_t)(wave * 8 + lrow)) * (KST * 2)
                               + (size_t)t * 128 + lslot;
        gload16(g0,                          lbase + wave * 1024);
        gload16(g0 + (size_t)64 * (KST * 2), lbase + 8192 + wave * 1024);
    };

    const int rl   = lane & 15;
    const int koct = lane >> 4;
    const int sK0 = ((0 * 4 + koct) ^ (lane & 7)) << 4;
    const int sK1 = ((1 * 4 + koct) ^ (lane & 7)) << 4;

    STAGE((const char*)A, arow0, 0, bufA + 0);
    STAGE((const char*)B, brow0, 0, bufB + 0);
    STAGE((const char*)A, arow0, 1, bufA + 16384);
    STAGE((const char*)B, brow0, 1, bufB + 16384);
    asm volatile("s_waitcnt vmcnt(4)" ::: "memory");
    __builtin_amdgcn_s_barrier();

    f32x4 acc[4][2] = {};

    for (int t = 0; t < NT; ++t) {
        char* const aC = bufA + (t & 1) * 16384;
        char* const bC = bufB + (t & 1) * 16384;

        bf16x8 af[4][2], bfr[2][2];
        #pragma unroll
        for (int m = 0; m < 4; ++m) {
            const int r = wr * 64 + m * 16 + rl;
            af[m][0] = *(const bf16x8*)(aC + r * 128 + sK0);
            af[m][1] = *(const bf16x8*)(aC + r * 128 + sK1);
        }
        #pragma unroll
        for (int n = 0; n < 2; ++n) {
            const int r = wc * 32 + n * 16 + rl;
            bfr[n][0] = *(const bf16x8*)(bC + r * 128 + sK0);
            bfr[n][1] = *(const bf16x8*)(bC + r * 128 + sK1);
        }
        asm volatile("s_waitcnt lgkmcnt(0)" ::: "memory");
        __builtin_amdgcn_sched_barrier(0);
        __builtin_amdgcn_s_barrier();

        if (t + 2 < NT) {
            STAGE((const char*)A, arow0, t + 2, aC);
            STAGE((const char*)B, brow0, t + 2, bC);
        }

        __builtin_amdgcn_s_setprio(1);
        #pragma unroll
        for (int ks = 0; ks < 2; ++ks)
            #pragma unroll
            for (int m = 0; m < 4; ++m)
                #pragma unroll
                for (int n = 0; n < 2; ++n)
                    acc[m][n] = __builtin_amdgcn_mfma_f32_16x16x32_bf16(
                        bfr[n][ks], af[m][ks], acc[m][n], 0, 0, 0);
        __builtin_amdgcn_s_setprio(0);
        __builtin_amdgcn_sched_barrier(0);

        if (t < NT - 2)       asm volatile("s_waitcnt vmcnt(4)" ::: "memory");
        else if (t == NT - 2) asm volatile("s_waitcnt vmcnt(0)" ::: "memory");
        if (t < NT - 1) __builtin_amdgcn_s_barrier();
    }

    #pragma unroll
    for (int h = 0; h < 2; ++h) {
        __syncthreads();
        if (wr == h) {
            #pragma unroll
            for (int m = 0; m < 4; ++m) {
                const int row_l = m * 16 + rl;
                #pragma unroll
                for (int n = 0; n < 2; ++n) {
                    const int col = wc * 32 + n * 16 + koct * 4;
                    *(f32x4*)&s_c[row_l * 132 + col] = acc[m][n];
                }
            }
        }
        __syncthreads();
        #pragma unroll
        for (int rr = 0; rr < 4; ++rr) {
            const int idx  = rr * 512 + tid;
            const int row  = idx >> 5;
            const int g4   = (idx & 31) * 4;
            if ((int)brow0 + g4 < OCOLS) {
                const f32x4 v = *(const f32x4*)&s_c[row * 132 + g4];
                __builtin_nontemporal_store(v,
                    (f32x4*)(C + (size_t)(arow0 + h * 64 + row) * OCOLS + brow0 + g4));
            }
        }
    }
}

// ---------------------------------------------------------------------------
extern "C" void kernel_launch(void* const* d_in, const int* in_sizes, int n_in,
                              void* d_out, int out_size, void* d_ws, size_t ws_size,
                              hipStream_t stream)
{
    const float* sk  = (const float*)d_in[0];   // (16,16,125,12)
    const float* ang = (const float*)d_in[1];   // (32000,25)
    const float* W   = (const float*)d_in[2];   // (12,720)
    const float* TP  = (const float*)d_in[3];   // (2704,2704)
    float* out = (float*)d_out;                 // (32000,2704)

    __hip_bfloat16* X   = (__hip_bfloat16*)d_ws;              // 20.5 MB
    __hip_bfloat16* Vb  = X   + (size_t)N_ROWS * KST;         // 1.8 MB
    __hip_bfloat16* TPb = Vb  + (size_t)OPAD * KST;           // 15.3 MB
    __hip_bfloat16* Gt  = TPb + (size_t)OPAD * KP;            // 1.74 MB

    prep1<<<NB_CVT + NB_G, 256, 0, stream>>>(TP, W, TPb, Gt);

    fused_V_X<<<NBV + NB_X, 256, 0, stream>>>(TPb, Gt, Vb, sk, ang, X);

    dim3 grid(OPAD / 128, N_ROWS / 128);   // (22, 250)
    gemm_bt<<<grid, 512, 0, stream>>>(X, Vb, out);
}